// Round 11
// baseline (178.017 us; speedup 1.0000x reference)
//
#include <hip/hip_runtime.h>

typedef unsigned short u16;
typedef __attribute__((ext_vector_type(8))) short short8;   // 8 bf16 (4 VGPRs) MFMA A/B frag
typedef __attribute__((ext_vector_type(4))) short shortx4;  // 4 bf16 (8B)
typedef __attribute__((ext_vector_type(4))) float floatx4;  // MFMA C/D frag

#define S_ 2048
#define D_ 1024
#define DQKV_ 3072
#define H_ 16
#define DH_ 64

#define EXP2F(x) __builtin_amdgcn_exp2f(x)
#define SBAR asm volatile("s_barrier" ::: "memory")  // barrier with IR-level memory ordering,
                                                     // NO waitcnt insertion (prefetch survives)

template <bool B> struct BoolC { static constexpr bool value = B; };
template <int I>  struct IntC  { static constexpr int  value = I; };

__device__ __forceinline__ float bf2f(u16 x) {
    union { unsigned int u; float f; } v; v.u = ((unsigned int)x) << 16; return v.f;
}
__device__ __forceinline__ u16 f2bf(float f) {  // RNE
    unsigned int u = __float_as_uint(f);
    return (u16)((u + 0x7fffu + ((u >> 16) & 1u)) >> 16);
}
// pack 2 f32 -> 2 bf16 in one u32 (D.lo = lo, D.hi = hi); no builtin on gfx950
__device__ __forceinline__ unsigned int cvtpk_bf16(float lo, float hi) {
    unsigned int r;
    asm("v_cvt_pk_bf16_f32 %0, %1, %2" : "=v"(r) : "v"(lo), "v"(hi));
    return r;
}

// async global->LDS, 16B per lane; LDS dest is wave-uniform base + lane*16 (m97/m104)
__device__ __forceinline__ void async16(const void* g, void* l) {
    __builtin_amdgcn_global_load_lds(
        (const __attribute__((address_space(1))) unsigned int*)g,
        (__attribute__((address_space(3))) unsigned int*)l, 16, 0, 0);
}

// ---- prep: fused convert_x (z=4..7) + W transposes (z=0..3) ----
__global__ __launch_bounds__(256) void prep(const float* __restrict__ x,
                                            const float* __restrict__ Wq, const float* __restrict__ Wk,
                                            const float* __restrict__ Wv, const float* __restrict__ Wo,
                                            u16* __restrict__ xb, u16* __restrict__ Wqkvt, u16* __restrict__ Wot) {
    __shared__ u16 tile[32][33];
    const int z = blockIdx.z;
    const int tx = threadIdx.x, ty = threadIdx.y;
    if (z >= 4) {  // convert_x path: slice (z-4), 1024 blocks x 256 thr x 4 floats
        const int t = ty * 32 + tx;
        const size_t bid = (size_t)(z - 4) * 1024 + blockIdx.y * 32 + blockIdx.x;
        const size_t i = (bid * 256 + t) * 4;
        float4 v = *(const float4*)&x[i];
        shortx4 h;
        h[0] = (short)f2bf(v.x); h[1] = (short)f2bf(v.y);
        h[2] = (short)f2bf(v.z); h[3] = (short)f2bf(v.w);
        *(shortx4*)&xb[i] = h;
        return;
    }
    const float* W = (z == 0) ? Wq : (z == 1) ? Wk : (z == 2) ? Wv : Wo;
    u16* dst = (z == 3) ? Wot : (Wqkvt + (size_t)z * D_ * D_);
    const int n0 = blockIdx.x * 32, k0 = blockIdx.y * 32;
#pragma unroll
    for (int r = 0; r < 4; ++r) {
        int k = ty + r * 8;
        tile[k][tx] = f2bf(W[(size_t)(k0 + k) * D_ + n0 + tx]);
    }
    __syncthreads();
#pragma unroll
    for (int r = 0; r < 4; ++r) {
        int n = ty + r * 8;
        dst[(size_t)(n0 + n) * D_ + k0 + tx] = tile[tx][n];
    }
}

// ------- Vt[bh][d][s] with sigma key-permutation within each 64-key block -------
// Position p holds original key sigma(p) = 32*(p>>5) + 16*((p>>2)&1) + 4*((p>>3)&3) + (p&3).
// Co-designed with attn's SWAPPED QK^T (P stays in registers). Kept as a separate
// kernel — fusing into the GEMM epilogue (R6) polluted L2 (+15us on the gemm).
__global__ __launch_bounds__(256) void transpose_headV(const u16* __restrict__ QKV, u16* __restrict__ Vt) {
    __shared__ u16 tile[64 * 65];
    const int t = threadIdx.x;
    const int bh = blockIdx.y, b = bh >> 4, h = bh & 15;
    const int s0 = blockIdx.x << 6;
#pragma unroll
    for (int i = 0; i < 16; ++i) {
        int idx = t + (i << 8);
        int s = idx >> 6, d = idx & 63;
        tile[s * 65 + d] = QKV[(size_t)(b * S_ + s0 + s) * DQKV_ + 2048 + h * DH_ + d];
    }
    __syncthreads();
#pragma unroll
    for (int i = 0; i < 16; ++i) {
        int idx = t + (i << 8);
        int d = idx >> 6, p = idx & 63;
        int sk = ((p >> 5) << 5) | (((p >> 2) & 1) << 4) | (((p >> 3) & 3) << 2) | (p & 3);
        Vt[((size_t)bh * DH_ + d) * S_ + s0 + p] = tile[sk * 65 + d];
    }
}

// ------- R10/R11: 256x256-tile 8-wave phase-interleaved GEMM (QKV projection) -------
// (R10 bench was an infra failure — resubmitted unchanged after re-audit.)
// C[M,3072] = A[M,1024] @ Bt[3072,1024]^T + bias, bf16 out. 512 thr = 8 waves
// (2M x 4N), per-wave 128x64 output, BK=64, LDS 2 x 64KB double-buffer (128KB,
// 1 block/CU). Rationale: at 128^2 the LDS pipe (256B/clk) is 2.3x oversubscribed
// vs MFMA; 256^2 halves frag-read replication per FLOP (ceiling MfmaUtil ~43->57%),
// and the per-phase barrier interleave (T3, m196/m218) recovers latency slack.
// LDS layout/swizzle = the attn-verified pair: staging pre-swizzles the global
// chunk ((lane&7)^(lane>>3)); reads XOR the chunk with (row&7) -> composes to
// identity (rule #21), 0 bank conflicts, verified in this kernel since R0.
// K-tile loop: boundary = R9-verified fused "s_waitcnt vmcnt(0); s_barrier" ONE
// asm (tile resident across ALL waves); next tile staged right after -> ~4 phases
// (600-1000cyc) of lead -> boundary drain cheap. Phases: quadrant order
// (r0c0)(r0c1)(r1c1)(r1c0) so A is reloaded once and B-halves alternate
// (28 b128/wave/K-tile). MFMA clusters wrapped in setprio (T5, pays at 8-phase).
// acc static-indexed via IntC (rule #20). launch_bounds(512,2) pins <=256 VGPR.
__global__ __launch_bounds__(512, 2) void gemm256(const u16* __restrict__ A, const u16* __restrict__ Bt,
                                                  const float* __restrict__ b0, const float* __restrict__ b1,
                                                  const float* __restrict__ b2, u16* __restrict__ Cp,
                                                  int N, int Kd) {
    __shared__ __align__(16) u16 smem[2][2 * 256 * 64];  // [buf][A(256x64) | B(256x64)]
    const int t = threadIdx.x;

    // XCD-aware bijective swizzle (nwg = 192, %8 == 0)
    const int nwg = gridDim.x * gridDim.y;
    int fid = blockIdx.y * gridDim.x + blockIdx.x;
    if ((nwg & 7) == 0) fid = (fid & 7) * (nwg >> 3) + (fid >> 3);
    const int bx = fid % gridDim.x, by = fid / gridDim.x;
    const int m0 = by * 256, n0 = bx * 256;

    const int w = t >> 6, lane = t & 63;
    const int lr = lane & 15, lg = lane >> 4;
    const int wm = (w >> 2) * 128, wn = (w & 3) * 64;   // per-wave 128x64 tile
    const int rb8 = lane >> 3;                          // staging row within 8-row group
    const int cc = ((lane & 7) ^ rb8) << 3;             // pre-swizzled source chunk (u16)
    const int swz = lr & 7;                             // read-side swizzle key (= row&7)

    floatx4 acc[8][4] = {};      // [row-tile i=0..7][col-tile j=0..3]
    short8 af[4][2], bfr[2][2];  // current quadrant's A (4 tiles x 2ks), B (2 tiles x 2ks)

    auto stage = [&](int buf, int k0) {  // wave w stages A rows [w*32,+32) and B rows [w*32,+32)
        u16* As = &smem[buf][0];
        u16* Bs = &smem[buf][256 * 64];
#pragma unroll
        for (int g = 0; g < 4; ++g) {
            async16(&A[(size_t)(m0 + w * 32 + g * 8 + rb8) * Kd + k0 + cc], &As[(w * 32 + g * 8) * 64]);
            async16(&Bt[(size_t)(n0 + w * 32 + g * 8 + rb8) * Kd + k0 + cc], &Bs[(w * 32 + g * 8) * 64]);
        }
    };

    const int nk = Kd / 64;
    stage(0, 0);  // prologue: tile 0 in flight
    for (int kt = 0; kt < nk; ++kt) {
        const int cur = kt & 1;
        // K-tile boundary: ONE asm = counted-wait + barrier (R9-verified ordering).
        // All waves' tile-kt DMAs retired -> tile resident block-wide.
        asm volatile("s_waitcnt vmcnt(0)\n\ts_barrier" ::: "memory");
        if (kt + 1 < nk) stage(cur ^ 1, (kt + 1) * 64);  // ~4 phases of lead before next drain
        const u16* As = &smem[cur][0];
        const u16* Bs = &smem[cur][256 * 64];

        auto ldA = [&](int rh) {  // A-half rh: rows wm+rh*64 .. +63
#pragma unroll
            for (int i = 0; i < 4; ++i)
#pragma unroll
                for (int ks = 0; ks < 2; ++ks)
                    af[i][ks] = *(const short8*)&As[(wm + rh * 64 + i * 16 + lr) * 64 +
                                                    ((((ks << 2) + lg) ^ swz) << 3)];
        };
        auto ldB = [&](int ch) {  // B-half ch: cols wn+ch*32 .. +31
#pragma unroll
            for (int j = 0; j < 2; ++j)
#pragma unroll
                for (int ks = 0; ks < 2; ++ks)
                    bfr[j][ks] = *(const short8*)&Bs[(wn + ch * 32 + j * 16 + lr) * 64 +
                                                     ((((ks << 2) + lg) ^ swz) << 3)];
        };
        auto mm = [&](auto RH, auto CH) {  // 16 MFMA: quadrant (RH,CH) x K=64
            constexpr int rh = RH.value, chv = CH.value;
            __builtin_amdgcn_s_setprio(1);
#pragma unroll
            for (int i = 0; i < 4; ++i)
#pragma unroll
                for (int j = 0; j < 2; ++j)
#pragma unroll
                    for (int ks = 0; ks < 2; ++ks)
                        acc[rh * 4 + i][chv * 2 + j] =
                            __builtin_amdgcn_mfma_f32_16x16x32_bf16(af[i][ks], bfr[j][ks],
                                                                    acc[rh * 4 + i][chv * 2 + j], 0, 0, 0);
            __builtin_amdgcn_s_setprio(0);
        };

        ldA(0); ldB(0);
        SBAR; mm(IntC<0>{}, IntC<0>{}); SBAR;   // phase 0: (r0,c0)
        ldB(1);
        SBAR; mm(IntC<0>{}, IntC<1>{}); SBAR;   // phase 1: (r0,c1)  A held
        ldA(1);
        SBAR; mm(IntC<1>{}, IntC<1>{}); SBAR;   // phase 2: (r1,c1)  B held
        ldB(0);
        SBAR; mm(IntC<1>{}, IntC<0>{});         // phase 3: (r1,c0); boundary barrier follows
    }

    // --- LDS-staged coalesced bf16 epilogue (256x256 u16 = 128KB = whole smem) ---
    __syncthreads();  // full drain: all waves done with last tile's reads
    u16* Cs = &smem[0][0];
#pragma unroll
    for (int j = 0; j < 4; ++j) {
        int c = wn + j * 16 + lr;
        int col = n0 + c;
        const float* bp = (col < 1024) ? b0 : (col < 2048) ? b1 : b2;
        float bv = bp[col & 1023];
#pragma unroll
        for (int i = 0; i < 8; ++i)
#pragma unroll
            for (int ii = 0; ii < 4; ++ii) {
                int r = wm + i * 16 + lg * 4 + ii;
                Cs[r * 256 + (c ^ ((r & 15) << 3))] = f2bf(acc[i][j][ii] + bv);
            }
    }
    __syncthreads();
#pragma unroll
    for (int it = 0; it < 16; ++it) {  // 256 rows x 32 chunks / 512 thr
        int g = it * 512 + t;
        int r = g >> 5, c2 = g & 31;
        short8 vv = *(const short8*)&Cs[r * 256 + ((c2 * 8) ^ ((r & 15) << 3))];
        *(short8*)&Cp[(size_t)(m0 + r) * N + n0 + c2 * 8] = vv;
    }
}

// ------- out-gemm (R9-verified): C[M,N] = A @ Bt^T + bias; 64x128 tile, BK=32 -------
// TRIPLE-buffered, distance-2 prefetch, counted vmcnt(LPT=3) fused with s_barrier
// in ONE asm (R8/R9 race lessons). fp32 output path.
template <int BM, int BN, bool OUTF32>
__global__ __launch_bounds__(256) void gemm_bt(const u16* __restrict__ A, const u16* __restrict__ Bt,
                                               const float* __restrict__ b0, const float* __restrict__ b1,
                                               const float* __restrict__ b2, void* __restrict__ Cp,
                                               int M, int N, int Kd) {
    constexpr int FI = BM / 32, FJ = BN / 32;
    constexpr int LPT = BM / 64 + BN / 64;  // async16 per wave per K-tile
    static_assert(LPT == 3 || LPT == 4, "vmcnt immediate must match LPT");
    __shared__ __align__(16) u16 smem[3][(BM + BN) * 32];
    const int t = threadIdx.x;

    const int nwg = gridDim.x * gridDim.y;
    int fid = blockIdx.y * gridDim.x + blockIdx.x;
    if ((nwg & 7) == 0) fid = (fid & 7) * (nwg >> 3) + (fid >> 3);
    const int bx = fid % gridDim.x, by = fid / gridDim.x;
    const int m0 = by * BM, n0 = bx * BN;

    const int w = t >> 6, lane = t & 63;
    const int lr = lane & 15, lg = lane >> 4;
    const int wm = (w >> 1) * (BM / 2), wn = (w & 1) * (BN / 2);
    const int srow = lane >> 2, scol = (lane & 3) << 3;
    floatx4 acc[FI][FJ] = {};

    auto stage = [&](int buf, int k0) {
        u16* As = &smem[buf][0];
        u16* Bs = &smem[buf][BM * 32];
#pragma unroll
        for (int c = 0; c < BM / 64; ++c) {
            int rbase = (w * (BM / 64) + c) * 16;
            async16(&A[(size_t)(m0 + rbase + srow) * Kd + k0 + scol], &As[rbase * 32]);
        }
#pragma unroll
        for (int c = 0; c < BN / 64; ++c) {
            int rbase = (w * (BN / 64) + c) * 16;
            async16(&Bt[(size_t)(n0 + rbase + srow) * Kd + k0 + scol], &Bs[rbase * 32]);
        }
    };

    const int nk = Kd / 32;
    stage(0, 0);
    stage(1, 32);
    for (int kk = 0; kk < nk; ++kk) {
        const int cur = kk % 3;
        if (kk + 1 < nk) {
            if constexpr (LPT == 4) asm volatile("s_waitcnt vmcnt(4)\n\ts_barrier" ::: "memory");
            else                    asm volatile("s_waitcnt vmcnt(3)\n\ts_barrier" ::: "memory");
        } else {
            asm volatile("s_waitcnt vmcnt(0)\n\ts_barrier" ::: "memory");
        }
        if (kk + 2 < nk) stage((kk + 2) % 3, (kk + 2) * 32);
        const u16* As = &smem[cur][0];
        const u16* Bs = &smem[cur][BM * 32];

        short8 af[FI], bfr[FJ];
#pragma unroll
        for (int i = 0; i < FI; ++i) af[i]  = *(const short8*)&As[(wm + i * 16 + lr) * 32 + lg * 8];
#pragma unroll
        for (int j = 0; j < FJ; ++j) bfr[j] = *(const short8*)&Bs[(wn + j * 16 + lr) * 32 + lg * 8];
#pragma unroll
        for (int i = 0; i < FI; ++i)
#pragma unroll
            for (int j = 0; j < FJ; ++j)
                acc[i][j] = __builtin_amdgcn_mfma_f32_16x16x32_bf16(af[i], bfr[j], acc[i][j], 0, 0, 0);
    }

    if (!OUTF32) {
        __syncthreads();
        u16* Cs = &smem[0][0];
#pragma unroll
        for (int j = 0; j < FJ; ++j) {
            int c = wn + j * 16 + lr;
            int col = n0 + c;
            const float* bp = (col < 1024) ? b0 : (col < 2048) ? b1 : b2;
            float bv = bp[col & 1023];
#pragma unroll
            for (int i = 0; i < FI; ++i)
#pragma unroll
                for (int ii = 0; ii < 4; ++ii) {
                    int r = wm + i * 16 + lg * 4 + ii;
                    Cs[r * BN + (c ^ ((r & 15) << 3))] = f2bf(acc[i][j][ii] + bv);
                }
        }
        __syncthreads();
        constexpr int CPR = BN / 8;
        constexpr int ITER = BM * CPR / 256;
#pragma unroll
        for (int it = 0; it < ITER; ++it) {
            int g = it * 256 + t;
            int r = g / CPR, c3 = g % CPR;
            short8 vv = *(const short8*)&Cs[r * BN + ((c3 * 8) ^ ((r & 15) << 3))];
            *(short8*)((u16*)Cp + (size_t)(m0 + r) * N + n0 + c3 * 8) = vv;
        }
    } else {
#pragma unroll
        for (int j = 0; j < FJ; ++j) {
            int col = n0 + wn + j * 16 + lr;
            const float* bp = (col < 1024) ? b0 : (col < 2048) ? b1 : b2;
            float bv = bp[col & 1023];
#pragma unroll
            for (int i = 0; i < FI; ++i) {
                int rb = m0 + wm + i * 16 + lg * 4;
#pragma unroll
                for (int ii = 0; ii < 4; ++ii)
                    ((float*)Cp)[(size_t)(rb + ii) * N + col] = acc[i][j][ii] + bv;
            }
        }
    }
}

// ---------------- MFMA flash attention: swapped-QK^T, P in-register, split-KQ waves ----------------
// grid (bh=32, y=32). 256-thr blocks. Waves split 2x2 over (q-half wq, key-half wk);
// K/V staging, XOR swizzle, sigma-permuted V, in-register P (verified R3/R5 paths).
// Two key-halves merge once at the end via 16KB LDS reduction. Balanced qt remap.
__global__ __launch_bounds__(256, 4) void attn_mfma(const u16* __restrict__ QKV, const u16* __restrict__ Vt,
                                                    u16* __restrict__ O) {
    __shared__ __align__(16) u16 KsA[2][64 * 64];  // [key][d], packed 128B rows, XOR-swizzled chunks
    __shared__ __align__(16) u16 VsA[2][64 * 64];  // [d][key-permuted]
    const int t = threadIdx.x, w = t >> 6, lane = t & 63;
    const int lr = lane & 15, lg = lane >> 4;
    const int wq = w & 1, wk = w >> 1;
    const int bh = blockIdx.x, b = bh >> 4, h = bh & 15;
    const int ya = blockIdx.y & 7, yb = blockIdx.y >> 3;
    const int a4 = (ya + 4) & 7;
    const int cq = (yb == 0) ? ya : (yb == 1) ? (7 - ya) : (yb == 2) ? a4 : (7 - a4);
    const int qt = (yb << 3) + cq;
    const int q0 = qt << 6;
    const float cs = 0.18033688f;  // (1/sqrt(64)) * log2(e)

    const u16* Kb  = QKV + (size_t)b * S_ * DQKV_ + 1024 + h * DH_;  // row stride DQKV_
    const u16* Vtb = Vt + (size_t)bh * DH_ * S_;                     // row stride S_

    const int rb8 = lane >> 3;               // row within 8-row staging group
    const int cc = ((lane & 7) ^ rb8) << 3;  // swizzled source chunk (u16 offset)
    const int swz = lr & 7;                  // frag-read swizzle key (= row&7)

    short8 qf[2][2];  // Q frags (B-operand): [qs][ks] rows q0+wq*32+qs*16+lr, d-chunk ks*32+lg*8
#pragma unroll
    for (int qs = 0; qs < 2; ++qs)
#pragma unroll
        for (int ks = 0; ks < 2; ++ks)
            qf[qs][ks] = *(const short8*)&QKV[(size_t)(b * S_ + q0 + wq * 32 + qs * 16 + lr) * DQKV_ +
                                              h * DH_ + ks * 32 + lg * 8];

    floatx4 of[2][4] = {};   // O-partial [qs][ttd]: row(q16)=lg*4+ii, col(d)=ttd*16+lr
    float lsum[2] = {0.f, 0.f};  // per-lane row-sum partial, per q-subblock

    auto stage = [&](int buf, int kbase) {
        u16* Kd = &KsA[buf][w * 512];  // wave w stages rows w*8.. and 32+w*8.. (K and V)
        u16* Vd = &VsA[buf][w * 512];
        async16(&Kb[(size_t)(kbase + w * 8 + rb8) * DQKV_ + cc], Kd);
        async16(&Kb[(size_t)(kbase + 32 + w * 8 + rb8) * DQKV_ + cc], Kd + 2048);
        async16(&Vtb[(size_t)(w * 8 + rb8) * S_ + kbase + cc], Vd);
        async16(&Vtb[(size_t)(32 + w * 8 + rb8) * S_ + kbase + cc], Vd + 2048);
    };

    stage(0, 0);  // prologue: DMA tile 0 into buffer 0

    auto body = [&](int kb, auto diagc) {
        constexpr bool DIAG = decltype(diagc)::value;
        const int cur = kb & 1;
        __syncthreads();  // implicit vmcnt(0) drain: buffer `cur` is ready
        if (kb < qt) stage(cur ^ 1, (kb + 1) << 6);  // prefetch overlaps compute below
        const u16* Kc = KsA[cur];
        const u16* Vc = VsA[cur];

        // S^T = K @ Q^T on this wave's quadrant: sf[qs][tt]
        floatx4 sf[2][2] = {};
        __builtin_amdgcn_s_setprio(1);
#pragma unroll
        for (int ks = 0; ks < 2; ++ks)
#pragma unroll
            for (int tt = 0; tt < 2; ++tt) {
                short8 kf = *(const short8*)&Kc[(wk * 32 + tt * 16 + lr) * 64 + ((((ks << 2) + lg) ^ swz) << 3)];
                sf[0][tt] = __builtin_amdgcn_mfma_f32_16x16x32_bf16(kf, qf[0][ks], sf[0][tt], 0, 0, 0);
                sf[1][tt] = __builtin_amdgcn_mfma_f32_16x16x32_bf16(kf, qf[1][ks], sf[1][tt], 0, 0, 0);
            }
        __builtin_amdgcn_s_setprio(0);

        // no-max softmax, per-lane: e = 2^(s*cs); masked -> 0 (diag tile only)
        float ev[2][2][4];
#pragma unroll
        for (int qs = 0; qs < 2; ++qs)
#pragma unroll
            for (int tt = 0; tt < 2; ++tt) {
                float s0;
#pragma unroll
                for (int ii = 0; ii < 4; ++ii) {
                    float e = EXP2F(sf[qs][tt][ii] * cs);
                    if (DIAG && (wk * 32 + tt * 16 + lg * 4 + ii > wq * 32 + qs * 16 + lr)) e = 0.f;
                    ev[qs][tt][ii] = e;
                    s0 = (ii == 0) ? e : s0 + e;
                }
                lsum[qs] += s0;
            }

        // PV partial (positions ks=wk only): A = lane's own e's (sigma alignment),
        // B = V rows, chunk (wk,lg).
        short8 vfr[4];
#pragma unroll
        for (int ttd = 0; ttd < 4; ++ttd)
            vfr[ttd] = *(const short8*)&Vc[(ttd * 16 + lr) * 64 + ((((wk << 2) + lg) ^ swz) << 3)];
        __builtin_amdgcn_s_setprio(1);
#pragma unroll
        for (int qs = 0; qs < 2; ++qs) {
            union { short8 s; unsigned int u[4]; } pk;
            pk.u[0] = cvtpk_bf16(ev[qs][0][0], ev[qs][0][1]);
            pk.u[1] = cvtpk_bf16(ev[qs][0][2], ev[qs][0][3]);
            pk.u[2] = cvtpk_bf16(ev[qs][1][0], ev[qs][1][1]);
            pk.u[3] = cvtpk_bf16(ev[qs][1][2], ev[qs][1][3]);
#pragma unroll
            for (int ttd = 0; ttd < 4; ++ttd)
                of[qs][ttd] = __builtin_amdgcn_mfma_f32_16x16x32_bf16(pk.s, vfr[ttd], of[qs][ttd], 0, 0, 0);
        }
        __builtin_amdgcn_s_setprio(0);
    };

    for (int kb = 0; kb < qt; ++kb) body(kb, BoolC<false>{});  // full tiles: no mask code
    body(qt, BoolC<true>{});                                   // diagonal tile: masked

    // ---- merge the two key-halves (once): wk=1 waves publish, wk=0 waves reduce ----
    __syncthreads();  // all waves done with K/V LDS; reuse as merge buffers
    float* mb = (float*)&KsA[0][0];
    float* lb = (float*)&VsA[0][0];
    if (wk == 1) {
        float* mw = mb + wq * 2048;
#pragma unroll
        for (int qs = 0; qs < 2; ++qs)
#pragma unroll
            for (int ttd = 0; ttd < 4; ++ttd)
                *(floatx4*)&mw[(qs * 4 + ttd) * 256 + lane * 4] = of[qs][ttd];
        lb[wq * 128 + lane * 2 + 0] = lsum[0];
        lb[wq * 128 + lane * 2 + 1] = lsum[1];
    }
    __syncthreads();
    if (wk == 0) {
        float* mw = mb + wq * 2048;
#pragma unroll
        for (int qs = 0; qs < 2; ++qs)
#pragma unroll
            for (int ttd = 0; ttd < 4; ++ttd)
                of[qs][ttd] += *(const floatx4*)&mw[(qs * 4 + ttd) * 256 + lane * 4];
        lsum[0] += lb[wq * 128 + lane * 2 + 0];
        lsum[1] += lb[wq * 128 + lane * 2 + 1];

        float rv[2][4];
#pragma unroll
        for (int qs = 0; qs < 2; ++qs) {
            float s = lsum[qs];
            s += __shfl_xor(s, 16);
            s += __shfl_xor(s, 32);
            float rinv = 1.f / s;
#pragma unroll
            for (int ii = 0; ii < 4; ++ii)
                rv[qs][ii] = __shfl(rinv, (lane & 48) | (lg * 4 + ii));
        }
#pragma unroll
        for (int qs = 0; qs < 2; ++qs)
#pragma unroll
            for (int ttd = 0; ttd < 4; ++ttd)
#pragma unroll
                for (int ii = 0; ii < 4; ++ii)
                    O[(size_t)(b * S_ + q0 + wq * 32 + qs * 16 + lg * 4 + ii) * D_ + h * DH_ + ttd * 16 + lr] =
                        f2bf(of[qs][ttd][ii] * rv[qs][ii]);
    }
}

extern "C" void kernel_launch(void* const* d_in, const int* in_sizes, int n_in,
                              void* d_out, int out_size, void* d_ws, size_t ws_size,
                              hipStream_t stream) {
    (void)in_sizes; (void)n_in; (void)out_size; (void)ws_size;
    const float* x  = (const float*)d_in[0];
    const float* Wq = (const float*)d_in[1];
    const float* bq = (const float*)d_in[2];
    const float* Wk = (const float*)d_in[3];
    const float* bk = (const float*)d_in[4];
    const float* Wv = (const float*)d_in[5];
    const float* bv = (const float*)d_in[6];
    const float* Wo = (const float*)d_in[7];
    const float* bo = (const float*)d_in[8];

    // ws layout (u16 elems), 48 MB total:
    //   [0,3M) WqkvT  [3M,4M) WoT  [4M,16M) QKV  [16M,20M) Vt  [20M,24M) xbf -> reused as Am
    u16* ws    = (u16*)d_ws;
    u16* WqkvT = ws;
    u16* WoT   = ws + (size_t)3 * (1 << 20);
    u16* QKV   = ws + (size_t)4 * (1 << 20);
    u16* Vtm   = ws + (size_t)16 * (1 << 20);
    u16* xbf   = ws + (size_t)20 * (1 << 20);
    u16* Am    = ws + (size_t)20 * (1 << 20);

    // fused convert + W transposes
    prep<<<dim3(32, 32, 8), dim3(32, 8), 0, stream>>>(x, Wq, Wk, Wv, Wo, xbf, WqkvT, WoT);

    // QKV = xbf @ WqkvT^T + [bq|bk|bv]  (M=4096, N=3072) — 256^2 8-wave phase kernel
    gemm256<<<dim3(DQKV_ / 256, 4096 / 256), 512, 0, stream>>>(
        xbf, WqkvT, bq, bk, bv, QKV, DQKV_, 1024);

    transpose_headV<<<dim3(32, 32), 256, 0, stream>>>(QKV, Vtm);

    attn_mfma<<<dim3(32, 32), 256, 0, stream>>>(QKV, Vtm, Am);

    // out = Am @ WoT^T + bo  (M=4096, N=1024), fp32 out
    gemm_bt<64, 128, true><<<dim3(1024 / 128, 4096 / 64), 256, 0, stream>>>(
        Am, WoT, bo, bo, bo, d_out, 4096, 1024, 1024);
}

// Round 12
// 175.602 us; speedup vs baseline: 1.0138x; 1.0138x over previous
//
#include <hip/hip_runtime.h>

typedef unsigned short u16;
typedef __attribute__((ext_vector_type(8))) short short8;   // 8 bf16 (4 VGPRs) MFMA A/B frag
typedef __attribute__((ext_vector_type(4))) short shortx4;  // 4 bf16 (8B)
typedef __attribute__((ext_vector_type(4))) float floatx4;  // MFMA C/D frag

#define S_ 2048
#define D_ 1024
#define DQKV_ 3072
#define H_ 16
#define DH_ 64

#define EXP2F(x) __builtin_amdgcn_exp2f(x)

template <bool B> struct BoolC { static constexpr bool value = B; };

__device__ __forceinline__ float bf2f(u16 x) {
    union { unsigned int u; float f; } v; v.u = ((unsigned int)x) << 16; return v.f;
}
__device__ __forceinline__ u16 f2bf(float f) {  // RNE
    unsigned int u = __float_as_uint(f);
    return (u16)((u + 0x7fffu + ((u >> 16) & 1u)) >> 16);
}
// pack 2 f32 -> 2 bf16 in one u32 (D.lo = lo, D.hi = hi); no builtin on gfx950
__device__ __forceinline__ unsigned int cvtpk_bf16(float lo, float hi) {
    unsigned int r;
    asm("v_cvt_pk_bf16_f32 %0, %1, %2" : "=v"(r) : "v"(lo), "v"(hi));
    return r;
}

// async global->LDS, 16B per lane; LDS dest is wave-uniform base + lane*16 (m97/m104)
__device__ __forceinline__ void async16(const void* g, void* l) {
    __builtin_amdgcn_global_load_lds(
        (const __attribute__((address_space(1))) unsigned int*)g,
        (__attribute__((address_space(3))) unsigned int*)l, 16, 0, 0);
}

// ---- prep: fused convert_x (z=4..7) + W transposes (z=0..3) ----
__global__ __launch_bounds__(256) void prep(const float* __restrict__ x,
                                            const float* __restrict__ Wq, const float* __restrict__ Wk,
                                            const float* __restrict__ Wv, const float* __restrict__ Wo,
                                            u16* __restrict__ xb, u16* __restrict__ Wqkvt, u16* __restrict__ Wot) {
    __shared__ u16 tile[32][33];
    const int z = blockIdx.z;
    const int tx = threadIdx.x, ty = threadIdx.y;
    if (z >= 4) {  // convert_x path: slice (z-4), 1024 blocks x 256 thr x 4 floats
        const int t = ty * 32 + tx;
        const size_t bid = (size_t)(z - 4) * 1024 + blockIdx.y * 32 + blockIdx.x;
        const size_t i = (bid * 256 + t) * 4;
        float4 v = *(const float4*)&x[i];
        shortx4 h;
        h[0] = (short)f2bf(v.x); h[1] = (short)f2bf(v.y);
        h[2] = (short)f2bf(v.z); h[3] = (short)f2bf(v.w);
        *(shortx4*)&xb[i] = h;
        return;
    }
    const float* W = (z == 0) ? Wq : (z == 1) ? Wk : (z == 2) ? Wv : Wo;
    u16* dst = (z == 3) ? Wot : (Wqkvt + (size_t)z * D_ * D_);
    const int n0 = blockIdx.x * 32, k0 = blockIdx.y * 32;
#pragma unroll
    for (int r = 0; r < 4; ++r) {
        int k = ty + r * 8;
        tile[k][tx] = f2bf(W[(size_t)(k0 + k) * D_ + n0 + tx]);
    }
    __syncthreads();
#pragma unroll
    for (int r = 0; r < 4; ++r) {
        int n = ty + r * 8;
        dst[(size_t)(n0 + n) * D_ + k0 + tx] = tile[tx][n];
    }
}

// ------- Vt[bh][d][s] with sigma key-permutation within each 64-key block -------
// Position p holds original key sigma(p) = 32*(p>>5) + 16*((p>>2)&1) + 4*((p>>3)&3) + (p&3).
// Co-designed with attn's SWAPPED QK^T (P stays in registers). Kept as a separate
// kernel — fusing into the GEMM epilogue (R6) polluted L2 (+15us on the gemm).
__global__ __launch_bounds__(256) void transpose_headV(const u16* __restrict__ QKV, u16* __restrict__ Vt) {
    __shared__ u16 tile[64 * 65];
    const int t = threadIdx.x;
    const int bh = blockIdx.y, b = bh >> 4, h = bh & 15;
    const int s0 = blockIdx.x << 6;
#pragma unroll
    for (int i = 0; i < 16; ++i) {
        int idx = t + (i << 8);
        int s = idx >> 6, d = idx & 63;
        tile[s * 65 + d] = QKV[(size_t)(b * S_ + s0 + s) * DQKV_ + 2048 + h * DH_ + d];
    }
    __syncthreads();
#pragma unroll
    for (int i = 0; i < 16; ++i) {
        int idx = t + (i << 8);
        int d = idx >> 6, p = idx & 63;
        int sk = ((p >> 5) << 5) | (((p >> 2) & 1) << 4) | (((p >> 3) & 3) << 2) | (p & 3);
        Vt[((size_t)bh * DH_ + d) * S_ + s0 + p] = tile[sk * 65 + d];
    }
}

// ------- C[M,N] = A[M,K] @ Bt[N,K]^T + bias; bf16 in, fp32 acc -------
// BMxBN tile, BK=32, 4 waves in 2x2 grid. FINAL (R9-verified, best=177.1us).
// TRIPLE-buffered async-DMA, prefetch distance 2, COUNTED vmcnt (T4), count
// PER-TEMPLATE-INSTANCE: LPT = BM/64 + BN/64 DMAs/wave/tile. Steady wait =
// vmcnt(LPT): retires all of tile kk, keeps tile kk+1 in flight. The counted
// wait + s_barrier are ONE indivisible asm with "memory" clobber — raw
// s_barrier has no IR-level memory ordering (R7's race: hoisted ds_reads read
// rows other waves' DMAs hadn't landed; vmcnt counts only the issuing wave).
// R11 confirmed 128^2 is the shape-correct tile: 256^2 gives 192 blocks < 256
// CUs (25% idle) and nets null despite +30% per-CU MfmaUtil.
// LDS 3x16KB(BM=128)=48KB -> 3 blocks/CU. Kept from R3: bijective XCD swizzle;
// LDS-staged coalesced bf16 epilogue (kills write-RMW amplification).
template <int BM, int BN, bool OUTF32>
__global__ __launch_bounds__(256) void gemm_bt(const u16* __restrict__ A, const u16* __restrict__ Bt,
                                               const float* __restrict__ b0, const float* __restrict__ b1,
                                               const float* __restrict__ b2, void* __restrict__ Cp,
                                               int M, int N, int Kd) {
    constexpr int FI = BM / 32, FJ = BN / 32;
    constexpr int LPT = BM / 64 + BN / 64;  // async16 per wave per K-tile
    static_assert(LPT == 3 || LPT == 4, "vmcnt immediate must match LPT");
    __shared__ __align__(16) u16 smem[3][(BM + BN) * 32];
    const int t = threadIdx.x;

    const int nwg = gridDim.x * gridDim.y;
    int fid = blockIdx.y * gridDim.x + blockIdx.x;
    if ((nwg & 7) == 0) fid = (fid & 7) * (nwg >> 3) + (fid >> 3);
    const int bx = fid % gridDim.x, by = fid / gridDim.x;
    const int m0 = by * BM, n0 = bx * BN;

    const int w = t >> 6, lane = t & 63;
    const int lr = lane & 15, lg = lane >> 4;
    const int wm = (w >> 1) * (BM / 2), wn = (w & 1) * (BN / 2);
    const int srow = lane >> 2, scol = (lane & 3) << 3;
    floatx4 acc[FI][FJ] = {};

    auto stage = [&](int buf, int k0) {
        u16* As = &smem[buf][0];
        u16* Bs = &smem[buf][BM * 32];
#pragma unroll
        for (int c = 0; c < BM / 64; ++c) {
            int rbase = (w * (BM / 64) + c) * 16;
            async16(&A[(size_t)(m0 + rbase + srow) * Kd + k0 + scol], &As[rbase * 32]);
        }
#pragma unroll
        for (int c = 0; c < BN / 64; ++c) {
            int rbase = (w * (BN / 64) + c) * 16;
            async16(&Bt[(size_t)(n0 + rbase + srow) * Kd + k0 + scol], &Bs[rbase * 32]);
        }
    };

    const int nk = Kd / 32;
    stage(0, 0);
    stage(1, 32);
    for (int kk = 0; kk < nk; ++kk) {
        const int cur = kk % 3;
        if (kk + 1 < nk) {
            if constexpr (LPT == 4) asm volatile("s_waitcnt vmcnt(4)\n\ts_barrier" ::: "memory");
            else                    asm volatile("s_waitcnt vmcnt(3)\n\ts_barrier" ::: "memory");
        } else {
            asm volatile("s_waitcnt vmcnt(0)\n\ts_barrier" ::: "memory");
        }
        if (kk + 2 < nk) stage((kk + 2) % 3, (kk + 2) * 32);
        const u16* As = &smem[cur][0];
        const u16* Bs = &smem[cur][BM * 32];

        short8 af[FI], bfr[FJ];
#pragma unroll
        for (int i = 0; i < FI; ++i) af[i]  = *(const short8*)&As[(wm + i * 16 + lr) * 32 + lg * 8];
#pragma unroll
        for (int j = 0; j < FJ; ++j) bfr[j] = *(const short8*)&Bs[(wn + j * 16 + lr) * 32 + lg * 8];
#pragma unroll
        for (int i = 0; i < FI; ++i)
#pragma unroll
            for (int j = 0; j < FJ; ++j)
                acc[i][j] = __builtin_amdgcn_mfma_f32_16x16x32_bf16(af[i], bfr[j], acc[i][j], 0, 0, 0);
    }

    if (!OUTF32) {
        __syncthreads();
        u16* Cs = &smem[0][0];
#pragma unroll
        for (int j = 0; j < FJ; ++j) {
            int c = wn + j * 16 + lr;
            int col = n0 + c;
            const float* bp = (col < 1024) ? b0 : (col < 2048) ? b1 : b2;
            float bv = bp[col & 1023];
#pragma unroll
            for (int i = 0; i < FI; ++i)
#pragma unroll
                for (int ii = 0; ii < 4; ++ii) {
                    int r = wm + i * 16 + lg * 4 + ii;
                    Cs[r * BN + (c ^ ((r & 15) << 3))] = f2bf(acc[i][j][ii] + bv);
                }
        }
        __syncthreads();
        constexpr int CPR = BN / 8;
        constexpr int ITER = BM * CPR / 256;
#pragma unroll
        for (int it = 0; it < ITER; ++it) {
            int g = it * 256 + t;
            int r = g / CPR, c3 = g % CPR;
            short8 vv = *(const short8*)&Cs[r * BN + ((c3 * 8) ^ ((r & 15) << 3))];
            *(short8*)((u16*)Cp + (size_t)(m0 + r) * N + n0 + c3 * 8) = vv;
        }
    } else {
#pragma unroll
        for (int j = 0; j < FJ; ++j) {
            int col = n0 + wn + j * 16 + lr;
            const float* bp = (col < 1024) ? b0 : (col < 2048) ? b1 : b2;
            float bv = bp[col & 1023];
#pragma unroll
            for (int i = 0; i < FI; ++i) {
                int rb = m0 + wm + i * 16 + lg * 4;
#pragma unroll
                for (int ii = 0; ii < 4; ++ii)
                    ((float*)Cp)[(size_t)(rb + ii) * N + col] = acc[i][j][ii] + bv;
            }
        }
    }
}

// ---------------- MFMA flash attention: swapped-QK^T, P in-register, split-KQ waves ----------------
// grid (bh=32, y=32). 256-thr blocks. Waves split 2x2 over (q-half wq, key-half wk);
// K/V staging, XOR swizzle, sigma-permuted V, in-register P (verified R3/R5 paths).
// Two key-halves merge once at the end via 16KB LDS reduction. Balanced qt remap.
__global__ __launch_bounds__(256, 4) void attn_mfma(const u16* __restrict__ QKV, const u16* __restrict__ Vt,
                                                    u16* __restrict__ O) {
    __shared__ __align__(16) u16 KsA[2][64 * 64];  // [key][d], packed 128B rows, XOR-swizzled chunks
    __shared__ __align__(16) u16 VsA[2][64 * 64];  // [d][key-permuted]
    const int t = threadIdx.x, w = t >> 6, lane = t & 63;
    const int lr = lane & 15, lg = lane >> 4;
    const int wq = w & 1, wk = w >> 1;
    const int bh = blockIdx.x, b = bh >> 4, h = bh & 15;
    const int ya = blockIdx.y & 7, yb = blockIdx.y >> 3;
    const int a4 = (ya + 4) & 7;
    const int cq = (yb == 0) ? ya : (yb == 1) ? (7 - ya) : (yb == 2) ? a4 : (7 - a4);
    const int qt = (yb << 3) + cq;
    const int q0 = qt << 6;
    const float cs = 0.18033688f;  // (1/sqrt(64)) * log2(e)

    const u16* Kb  = QKV + (size_t)b * S_ * DQKV_ + 1024 + h * DH_;  // row stride DQKV_
    const u16* Vtb = Vt + (size_t)bh * DH_ * S_;                     // row stride S_

    const int rb8 = lane >> 3;               // row within 8-row staging group
    const int cc = ((lane & 7) ^ rb8) << 3;  // swizzled source chunk (u16 offset)
    const int swz = lr & 7;                  // frag-read swizzle key (= row&7)

    short8 qf[2][2];  // Q frags (B-operand): [qs][ks] rows q0+wq*32+qs*16+lr, d-chunk ks*32+lg*8
#pragma unroll
    for (int qs = 0; qs < 2; ++qs)
#pragma unroll
        for (int ks = 0; ks < 2; ++ks)
            qf[qs][ks] = *(const short8*)&QKV[(size_t)(b * S_ + q0 + wq * 32 + qs * 16 + lr) * DQKV_ +
                                              h * DH_ + ks * 32 + lg * 8];

    floatx4 of[2][4] = {};   // O-partial [qs][ttd]: row(q16)=lg*4+ii, col(d)=ttd*16+lr
    float lsum[2] = {0.f, 0.f};  // per-lane row-sum partial, per q-subblock

    auto stage = [&](int buf, int kbase) {
        u16* Kd = &KsA[buf][w * 512];  // wave w stages rows w*8.. and 32+w*8.. (K and V)
        u16* Vd = &VsA[buf][w * 512];
        async16(&Kb[(size_t)(kbase + w * 8 + rb8) * DQKV_ + cc], Kd);
        async16(&Kb[(size_t)(kbase + 32 + w * 8 + rb8) * DQKV_ + cc], Kd + 2048);
        async16(&Vtb[(size_t)(w * 8 + rb8) * S_ + kbase + cc], Vd);
        async16(&Vtb[(size_t)(32 + w * 8 + rb8) * S_ + kbase + cc], Vd + 2048);
    };

    stage(0, 0);  // prologue: DMA tile 0 into buffer 0

    auto body = [&](int kb, auto diagc) {
        constexpr bool DIAG = decltype(diagc)::value;
        const int cur = kb & 1;
        __syncthreads();  // implicit vmcnt(0) drain: buffer `cur` is ready
        if (kb < qt) stage(cur ^ 1, (kb + 1) << 6);  // prefetch overlaps compute below
        const u16* Kc = KsA[cur];
        const u16* Vc = VsA[cur];

        // S^T = K @ Q^T on this wave's quadrant: sf[qs][tt]
        floatx4 sf[2][2] = {};
        __builtin_amdgcn_s_setprio(1);
#pragma unroll
        for (int ks = 0; ks < 2; ++ks)
#pragma unroll
            for (int tt = 0; tt < 2; ++tt) {
                short8 kf = *(const short8*)&Kc[(wk * 32 + tt * 16 + lr) * 64 + ((((ks << 2) + lg) ^ swz) << 3)];
                sf[0][tt] = __builtin_amdgcn_mfma_f32_16x16x32_bf16(kf, qf[0][ks], sf[0][tt], 0, 0, 0);
                sf[1][tt] = __builtin_amdgcn_mfma_f32_16x16x32_bf16(kf, qf[1][ks], sf[1][tt], 0, 0, 0);
            }
        __builtin_amdgcn_s_setprio(0);

        // no-max softmax, per-lane: e = 2^(s*cs); masked -> 0 (diag tile only)
        float ev[2][2][4];
#pragma unroll
        for (int qs = 0; qs < 2; ++qs)
#pragma unroll
            for (int tt = 0; tt < 2; ++tt) {
                float s0;
#pragma unroll
                for (int ii = 0; ii < 4; ++ii) {
                    float e = EXP2F(sf[qs][tt][ii] * cs);
                    if (DIAG && (wk * 32 + tt * 16 + lg * 4 + ii > wq * 32 + qs * 16 + lr)) e = 0.f;
                    ev[qs][tt][ii] = e;
                    s0 = (ii == 0) ? e : s0 + e;
                }
                lsum[qs] += s0;
            }

        // PV partial (positions ks=wk only): A = lane's own e's (sigma alignment),
        // B = V rows, chunk (wk,lg).
        short8 vfr[4];
#pragma unroll
        for (int ttd = 0; ttd < 4; ++ttd)
            vfr[ttd] = *(const short8*)&Vc[(ttd * 16 + lr) * 64 + ((((wk << 2) + lg) ^ swz) << 3)];
        __builtin_amdgcn_s_setprio(1);
#pragma unroll
        for (int qs = 0; qs < 2; ++qs) {
            union { short8 s; unsigned int u[4]; } pk;
            pk.u[0] = cvtpk_bf16(ev[qs][0][0], ev[qs][0][1]);
            pk.u[1] = cvtpk_bf16(ev[qs][0][2], ev[qs][0][3]);
            pk.u[2] = cvtpk_bf16(ev[qs][1][0], ev[qs][1][1]);
            pk.u[3] = cvtpk_bf16(ev[qs][1][2], ev[qs][1][3]);
#pragma unroll
            for (int ttd = 0; ttd < 4; ++ttd)
                of[qs][ttd] = __builtin_amdgcn_mfma_f32_16x16x32_bf16(pk.s, vfr[ttd], of[qs][ttd], 0, 0, 0);
        }
        __builtin_amdgcn_s_setprio(0);
    };

    for (int kb = 0; kb < qt; ++kb) body(kb, BoolC<false>{});  // full tiles: no mask code
    body(qt, BoolC<true>{});                                   // diagonal tile: masked

    // ---- merge the two key-halves (once): wk=1 waves publish, wk=0 waves reduce ----
    __syncthreads();  // all waves done with K/V LDS; reuse as merge buffers
    float* mb = (float*)&KsA[0][0];
    float* lb = (float*)&VsA[0][0];
    if (wk == 1) {
        float* mw = mb + wq * 2048;
#pragma unroll
        for (int qs = 0; qs < 2; ++qs)
#pragma unroll
            for (int ttd = 0; ttd < 4; ++ttd)
                *(floatx4*)&mw[(qs * 4 + ttd) * 256 + lane * 4] = of[qs][ttd];
        lb[wq * 128 + lane * 2 + 0] = lsum[0];
        lb[wq * 128 + lane * 2 + 1] = lsum[1];
    }
    __syncthreads();
    if (wk == 0) {
        float* mw = mb + wq * 2048;
#pragma unroll
        for (int qs = 0; qs < 2; ++qs)
#pragma unroll
            for (int ttd = 0; ttd < 4; ++ttd)
                of[qs][ttd] += *(const floatx4*)&mw[(qs * 4 + ttd) * 256 + lane * 4];
        lsum[0] += lb[wq * 128 + lane * 2 + 0];
        lsum[1] += lb[wq * 128 + lane * 2 + 1];

        float rv[2][4];
#pragma unroll
        for (int qs = 0; qs < 2; ++qs) {
            float s = lsum[qs];
            s += __shfl_xor(s, 16);
            s += __shfl_xor(s, 32);
            float rinv = 1.f / s;
#pragma unroll
            for (int ii = 0; ii < 4; ++ii)
                rv[qs][ii] = __shfl(rinv, (lane & 48) | (lg * 4 + ii));
        }
#pragma unroll
        for (int qs = 0; qs < 2; ++qs)
#pragma unroll
            for (int ttd = 0; ttd < 4; ++ttd)
#pragma unroll
                for (int ii = 0; ii < 4; ++ii)
                    O[(size_t)(b * S_ + q0 + wq * 32 + qs * 16 + lg * 4 + ii) * D_ + h * DH_ + ttd * 16 + lr] =
                        f2bf(of[qs][ttd][ii] * rv[qs][ii]);
    }
}

extern "C" void kernel_launch(void* const* d_in, const int* in_sizes, int n_in,
                              void* d_out, int out_size, void* d_ws, size_t ws_size,
                              hipStream_t stream) {
    (void)in_sizes; (void)n_in; (void)out_size; (void)ws_size;
    const float* x  = (const float*)d_in[0];
    const float* Wq = (const float*)d_in[1];
    const float* bq = (const float*)d_in[2];
    const float* Wk = (const float*)d_in[3];
    const float* bk = (const float*)d_in[4];
    const float* Wv = (const float*)d_in[5];
    const float* bv = (const float*)d_in[6];
    const float* Wo = (const float*)d_in[7];
    const float* bo = (const float*)d_in[8];

    // ws layout (u16 elems), 48 MB total:
    //   [0,3M) WqkvT  [3M,4M) WoT  [4M,16M) QKV  [16M,20M) Vt  [20M,24M) xbf -> reused as Am
    u16* ws    = (u16*)d_ws;
    u16* WqkvT = ws;
    u16* WoT   = ws + (size_t)3 * (1 << 20);
    u16* QKV   = ws + (size_t)4 * (1 << 20);
    u16* Vtm   = ws + (size_t)16 * (1 << 20);
    u16* xbf   = ws + (size_t)20 * (1 << 20);
    u16* Am    = ws + (size_t)20 * (1 << 20);

    // fused convert + W transposes
    prep<<<dim3(32, 32, 8), dim3(32, 8), 0, stream>>>(x, Wq, Wk, Wv, Wo, xbf, WqkvT, WoT);

    // QKV = xbf @ WqkvT^T + [bq|bk|bv]  (M=4096, N=3072)
    gemm_bt<128, 128, false><<<dim3(DQKV_ / 128, 4096 / 128), 256, 0, stream>>>(
        xbf, WqkvT, bq, bk, bv, QKV, 4096, DQKV_, 1024);

    transpose_headV<<<dim3(32, 32), 256, 0, stream>>>(QKV, Vtm);

    attn_mfma<<<dim3(32, 32), 256, 0, stream>>>(QKV, Vtm, Am);

    // out = Am @ WoT^T + bo  (M=4096, N=1024), fp32 out
    gemm_bt<64, 128, true><<<dim3(1024 / 128, 4096 / 64), 256, 0, stream>>>(
        Am, WoT, bo, bo, bo, d_out, 4096, 1024, 1024);
}